// Round 10
// baseline (83.463 us; speedup 1.0000x reference)
//
#include <hip/hip_runtime.h>
#include <hip/hip_bf16.h>

typedef unsigned short u16;
typedef float  floatx4 __attribute__((ext_vector_type(4)));
typedef short  bf16x8  __attribute__((ext_vector_type(8)));

#define GK 4352   // 4096 + 64 lora cols + 192 zero pad (= 4 * 17 * 64)

__device__ __forceinline__ u16 f2bf_rne(float f) {
  union { float f; unsigned int u; } v; v.f = f;
  unsigned int r = v.u + 0x7FFFu + ((v.u >> 16) & 1u);
  return (u16)(r >> 16);
}
__device__ __forceinline__ float bf2f(u16 h) {
  union { unsigned int u; float f; } v; v.u = ((unsigned int)h) << 16;
  return v.f;
}

// ===========================================================================
// In-register FWHT-4096 per block (4 waves): H4096 = H64(rows) (x) H64(cols).
// ===========================================================================
__device__ __forceinline__ void fwht4096_regs(float v[16], float* X, int w, int l) {
#pragma unroll
  for (int h = 1; h < 64; h <<= 1) {
#pragma unroll
    for (int k = 0; k < 16; ++k) {
      float o = __shfl_xor(v[k], h, 64);
      v[k] = (l & h) ? (o - v[k]) : (v[k] + o);
    }
  }
#pragma unroll
  for (int k = 0; k < 16; ++k) X[(w * 16 + k) * 64 + l] = v[k];
  __syncthreads();
  float s4 = (w & 1) ? -1.f : 1.f;
  float s5 = (w & 2) ? -1.f : 1.f;
#pragma unroll
  for (int k = 0; k < 16; ++k) {
    float x00 = X[(k     ) * 64 + l];
    float x01 = X[(k + 16) * 64 + l];
    float x10 = X[(k + 32) * 64 + l];
    float x11 = X[(k + 48) * 64 + l];
    v[k] = (x00 + s4 * x01) + s5 * (x10 + s4 * x11);
  }
#pragma unroll
  for (int h = 1; h < 16; h <<= 1) {
#pragma unroll
    for (int k = 0; k < 16; ++k) {
      if (!(k & h)) { float a = v[k], b = v[k ^ h]; v[k] = a + b; v[k ^ h] = a - b; }
    }
  }
}

// ---------------------------------------------------------------------------
// Kernel 1 (fused): grid 9280 blocks, block-uniform branch:
//  bid 0..1023   : u[s] = bf16( H(x[s] o SU) / 64 )          (fwht_u)
//  bid 1024..1087: Wd tail col 4096+r, K-pad zero, Bh[r]      (prep_lora)
//  bid 1088..9279: decode E8P -> Wd integer weights (bf16)    (decode)
// ---------------------------------------------------------------------------
__global__ __launch_bounds__(256) void prep_all_kernel(
    const float* __restrict__ x, const float* __restrict__ SU,
    const float* __restrict__ SV, const float* __restrict__ WscaleP,
    const float* __restrict__ loraA, const float* __restrict__ loraB,
    const int* __restrict__ codes, const int* __restrict__ grid,
    u16* __restrict__ Wd, u16* __restrict__ u, u16* __restrict__ Bh) {
  __shared__ float X[4096];
  int bid = blockIdx.x, t = threadIdx.x, l = t & 63, w = t >> 6;

  if (bid < 1024) {
    int s = bid;
    const float* xr = x + (size_t)s * 4096;
    float v[16];
#pragma unroll
    for (int k = 0; k < 16; ++k) {
      int i = (w * 16 + k) * 64 + l;
      v[k] = xr[i] * SU[i];
    }
    fwht4096_regs(v, X, w, l);
    __syncthreads();
    u16* Xu = (u16*)X;
#pragma unroll
    for (int k = 0; k < 16; ++k)
      Xu[(w * 16 + k) * 64 + l] = f2bf_rne(v[k] * 0.015625f);
    __syncthreads();
    u16* ur = u + (size_t)s * GK;
#pragma unroll
    for (int c = 0; c < 2; ++c) {
      int j = (t + 256 * c) * 8;
      *(uint4*)(ur + j) = *(const uint4*)(Xu + j);
    }
  } else if (bid < 1088) {
    int r = bid - 1024;
    float v[16];
#pragma unroll
    for (int k = 0; k < 16; ++k) {
      int i = (w * 16 + k) * 64 + l;
      v[k] = loraA[(size_t)i * 64 + r] * SV[i];
    }
    fwht4096_regs(v, X, w, l);
    float factor = (0.8f * 263.68f / 4096.0f) / WscaleP[0];
#pragma unroll
    for (int k = 0; k < 16; ++k) {
      int i = (w * 16 + k) * 64 + l;
      Wd[(size_t)i * GK + 4096 + r] = f2bf_rne(v[k] * factor);
    }
    {
      uint4 zv = make_uint4(0, 0, 0, 0);
#pragma unroll
      for (int j = 0; j < 6; ++j) {
        int idx = t + 256 * j;
        int row = idx / 24, cs = idx % 24;
        uint4* p = (uint4*)(Wd + (size_t)(r * 64 + row) * GK + 4160) + cs;
        *p = zv;
      }
    }
    __syncthreads();
#pragma unroll
    for (int k = 0; k < 16; ++k) {
      int i = (w * 16 + k) * 64 + l;
      v[k] = loraB[(size_t)r * 4096 + i] * SU[i];
    }
    fwht4096_regs(v, X, w, l);
#pragma unroll
    for (int k = 0; k < 16; ++k) {
      int i = (w * 16 + k) * 64 + l;
      Bh[(size_t)r * 4096 + i] = f2bf_rne(v[k] * 0.015625f);
    }
  } else {
    int* sgrid = (int*)X;
    sgrid[t] = grid[t & 255];
    __syncthreads();
    int idx = (bid - 1088) * 256 + t;
    int c = codes[idx];
    int abs_idx   = c & 255;
    int sign_bits = (c >> 8) & 127;
    int dlt       = 2 * ((c >> 15) & 1) - 1;
    int packed    = sgrid[abs_idx];
    int par       = __popc(sign_bits) & 1;
    u16 wv[8];
#pragma unroll
    for (int j = 0; j < 8; ++j) {
      int nib = (packed >> (4 * j)) & 15;
      int neg = (j < 7) ? ((sign_bits >> j) & 1) : par;
      int val = (neg ? -2 * nib : 2 * nib) + dlt;
      wv[j] = f2bf_rne((float)val);
    }
    uint4 pk;
    pk.x = (unsigned)wv[0] | ((unsigned)wv[1] << 16);
    pk.y = (unsigned)wv[2] | ((unsigned)wv[3] << 16);
    pk.z = (unsigned)wv[4] | ((unsigned)wv[5] << 16);
    pk.w = (unsigned)wv[6] | ((unsigned)wv[7] << 16);
    int m = idx >> 9, g = idx & 511;
    ((uint4*)Wd)[(size_t)m * (GK / 8) + g] = pk;
  }
}

// ---------------------------------------------------------------------------
// Staging helpers (16B global_load_lds, XOR-swizzled source; verified r2-r9)
// ---------------------------------------------------------------------------
__device__ __forceinline__ void stage128(const u16* __restrict__ src, int rowBase,
                                         int kt, char* ldsBase, int wg, int l) {
#pragma unroll
  for (int it = 0; it < 4; ++it) {
    int ci  = it * 4 + wg;
    int row = ci * 8 + (l >> 3);
    int cg  = (l & 7) ^ ((l >> 3) & 7);
    const u16* gp = src + (size_t)(rowBase + row) * GK + kt + cg * 8;
    __builtin_amdgcn_global_load_lds(
        (const __attribute__((address_space(1))) void*)gp,
        (__attribute__((address_space(3))) void*)(ldsBase + ci * 1024), 16, 0, 0);
  }
}
__device__ __forceinline__ void stage64n(const u16* __restrict__ src,
                                         int kt, char* ldsBase, int wg, int l) {
#pragma unroll
  for (int it = 0; it < 2; ++it) {
    int ci  = it * 4 + wg;
    int row = ci * 8 + (l >> 3);
    int cg  = (l & 7) ^ ((l >> 3) & 7);
    const u16* gp = src + (size_t)row * 4096 + kt + cg * 8;
    __builtin_amdgcn_global_load_lds(
        (const __attribute__((address_space(1))) void*)gp,
        (__attribute__((address_space(3))) void*)(ldsBase + ci * 1024), 16, 0, 0);
  }
}
// 128-row x 64-col HALF-tile, 8-wave (512 thr) block: 2 loads/thread, 16 KB.
__device__ __forceinline__ void stage_half(const u16* __restrict__ src, int rowBase,
                                           int kt, char* slotBase, int w, int l) {
#pragma unroll
  for (int it = 0; it < 2; ++it) {
    int ci  = it * 8 + w;
    int row = ci * 8 + (l >> 3);
    int cg  = (l & 7) ^ ((l >> 3) & 7);
    const u16* gp = src + (size_t)(rowBase + row) * GK + kt + cg * 8;
    __builtin_amdgcn_global_load_lds(
        (const __attribute__((address_space(1))) void*)gp,
        (__attribute__((address_space(3))) void*)(slotBase + ci * 1024), 16, 0, 0);
  }
}

// ---------------------------------------------------------------------------
// Kernel 2: lr partials. P[by][s][r] = sum_{k in chunk by} u[s,k]*Bh[r,k]
// ---------------------------------------------------------------------------
__global__ __launch_bounds__(256) void lr_gemm_kernel(
    const u16* __restrict__ U,    // [1024][GK]
    const u16* __restrict__ Bh,   // [64][4096]
    float* __restrict__ P) {      // [4][1024][64]
  __shared__ char lds[49152];
  int t = threadIdx.x, w = t >> 6, l = t & 63;
  int s0 = blockIdx.x * 128, k0 = blockIdx.y * 1024;
  int lr16 = l & 15, lk = l >> 4;
  char* ldsA = lds;
  char* ldsB = lds + 32768;

  floatx4 acc[2][4];
#pragma unroll
  for (int i = 0; i < 2; ++i)
#pragma unroll
    for (int j = 0; j < 4; ++j) acc[i][j] = (floatx4){0.f, 0.f, 0.f, 0.f};

  const int NT = 16;
  stage128(U,  s0, k0,      ldsA,         w, l);
  stage64n(Bh,     k0,      ldsB,         w, l);
  stage128(U,  s0, k0 + 64, ldsA + 16384, w, l);
  stage64n(Bh,     k0 + 64, ldsB + 8192,  w, l);
  asm volatile("s_waitcnt vmcnt(6)" ::: "memory");
  __builtin_amdgcn_s_barrier();

  for (int i = 0; i < NT; ++i) {
    int buf = i & 1;
    const char* sAc = ldsA + buf * 16384;
    const char* sBc = ldsB + buf * 8192;
    bf16x8 a[2][2], b[4][2];
#pragma unroll
    for (int ii = 0; ii < 2; ++ii)
#pragma unroll
      for (int ks = 0; ks < 2; ++ks) {
        int row = w * 32 + ii * 16 + lr16;
        int kb  = ks * 64 + lk * 16;
        a[ii][ks] = *(const bf16x8*)(sAc + (row << 7) + (kb ^ ((row & 7) << 4)));
      }
#pragma unroll
    for (int jj = 0; jj < 4; ++jj)
#pragma unroll
      for (int ks = 0; ks < 2; ++ks) {
        int row = jj * 16 + lr16;
        int kb  = ks * 64 + lk * 16;
        b[jj][ks] = *(const bf16x8*)(sBc + (row << 7) + (kb ^ ((row & 7) << 4)));
      }
    asm volatile("s_waitcnt lgkmcnt(0)" ::: "memory");
    __builtin_amdgcn_sched_barrier(0);
    bool do_stage = (i + 2) < NT;
    if (do_stage) {
      __builtin_amdgcn_s_barrier();
      stage128(U,  s0, k0 + (i + 2) * 64, ldsA + buf * 16384, w, l);
      stage64n(Bh,     k0 + (i + 2) * 64, ldsB + buf * 8192,  w, l);
    }
#pragma unroll
    for (int ks = 0; ks < 2; ++ks)
#pragma unroll
      for (int ii = 0; ii < 2; ++ii)
#pragma unroll
        for (int jj = 0; jj < 4; ++jj)
          acc[ii][jj] = __builtin_amdgcn_mfma_f32_16x16x32_bf16(
              a[ii][ks], b[jj][ks], acc[ii][jj], 0, 0, 0);
    if (i + 1 < NT) {
      if (do_stage) asm volatile("s_waitcnt vmcnt(6)" ::: "memory");
      else          asm volatile("s_waitcnt vmcnt(0)" ::: "memory");
      __builtin_amdgcn_s_barrier();
    }
  }
  float* Pb = P + (size_t)blockIdx.y * 65536;
#pragma unroll
  for (int ii = 0; ii < 2; ++ii)
#pragma unroll
    for (int jj = 0; jj < 4; ++jj) {
      int col  = jj * 16 + lr16;
      int rowb = s0 + w * 32 + ii * 16 + lk * 4;
#pragma unroll
      for (int q = 0; q < 4; ++q)
        Pb[(size_t)(rowb + q) * 64 + col] = acc[ii][jj][q];
    }
}

// ---------------------------------------------------------------------------
// Kernel 3: lr tail: u[s][4096+r] = bf16( sum_c P[c][s][r] ); zero 192-col pad.
// ---------------------------------------------------------------------------
__global__ void lr_reduce_kernel(const float* __restrict__ P, u16* __restrict__ u) {
  int idx = blockIdx.x * 256 + threadIdx.x;
  float s = P[idx] + P[65536 + idx] + P[131072 + idx] + P[196608 + idx];
  int ss = idx >> 6, rr = idx & 63;
  u16* row = u + (size_t)ss * GK;
  row[4096 + rr] = f2bf_rne(s);
  row[4160 + rr] = 0;
  row[4224 + rr] = 0;
  row[4288 + rr] = 0;
}

// ---------------------------------------------------------------------------
// Kernel 4: GEMM partials, 256x256 tile, 8 waves, K-split 4, DEEP pipeline:
// A triple-buffered (3x32KB) + B double-buffered (2x32KB) = 160 KiB LDS.
// Per tile (4 phases): ph1 read aF,bF | ph2 read aG | ph3 read bG + stage
// A(t+3) (buf (t+3)%3 = t%3, freed after ph2) | ph4 stage B(t+2) (freed
// after ph3) + vmcnt(8) (leaves A(t+3)+B(t+2) in flight; never drains).
// Issue-to-use: A 10 phases, B 5 phases >> HBM latency. Tail: vmcnt 4/0.
// ---------------------------------------------------------------------------
__device__ __forceinline__ void rda(bf16x8 (&dst)[4][2], const char* base, int roff,
                                    int lr16, int lk) {
#pragma unroll
  for (int ii = 0; ii < 4; ++ii)
#pragma unroll
    for (int ks = 0; ks < 2; ++ks) {
      int r = roff + ii * 16 + lr16;
      dst[ii][ks] = *(const bf16x8*)(base + (r << 7) +
          ((ks * 64 + lk * 16) ^ ((r & 7) << 4)));
    }
}
__device__ __forceinline__ void rdb(bf16x8 (&dst)[2][2], const char* base, int roff,
                                    int lr16, int lk) {
#pragma unroll
  for (int jj = 0; jj < 2; ++jj)
#pragma unroll
    for (int ks = 0; ks < 2; ++ks) {
      int r = roff + jj * 16 + lr16;
      dst[jj][ks] = *(const bf16x8*)(base + (r << 7) +
          ((ks * 64 + lk * 16) ^ ((r & 7) << 4)));
    }
}
template<int IO, int JO>
__device__ __forceinline__ void mfq(const bf16x8 (&af)[4][2], const bf16x8 (&bf)[2][2],
                                    floatx4 (&acc)[8][4]) {
  __builtin_amdgcn_s_setprio(1);
#pragma unroll
  for (int ks = 0; ks < 2; ++ks)
#pragma unroll
    for (int ii = 0; ii < 4; ++ii)
#pragma unroll
      for (int jj = 0; jj < 2; ++jj)
        acc[IO + ii][JO + jj] = __builtin_amdgcn_mfma_f32_16x16x32_bf16(
            af[ii][ks], bf[jj][ks], acc[IO + ii][JO + jj], 0, 0, 0);
  __builtin_amdgcn_s_setprio(0);
}
#define PH_PRE()  do { __builtin_amdgcn_s_barrier(); \
                       asm volatile("s_waitcnt lgkmcnt(0)" ::: "memory"); } while (0)
#define PH_POST() __builtin_amdgcn_s_barrier()

__global__ __launch_bounds__(512, 2) void gemm_kernel(
    const u16* __restrict__ A,    // u  [1024][GK]
    const u16* __restrict__ Bm,   // Wd [4096][GK]
    u16* __restrict__ zO,         // [1024][2][4096] bf16 (aliases d_out)
    u16* __restrict__ zW) {       // [1024][2][4096] bf16 (ws)
  __shared__ char lds[163840];    // A: 3 bufs x 32KB @0 | B: 2 bufs x 32KB @98304
  int t = threadIdx.x, w = t >> 6, l = t & 63;
  int b = blockIdx.x;
  int xcd = b & 7, slot = b >> 3;
  int cell = slot >> 4, j4 = slot & 15;
  int x = (xcd & 3) * 4 + (j4 & 3);           // m-tile 0..15
  int g = (xcd >> 2) + 2 * cell;              // k-split 0..3
  int y = j4 >> 2;                            // s-tile 0..3
  int m0 = x * 256, s0 = y * 256;
  int wsd = w >> 2, wmd = w & 3;
  int lr16 = l & 15, lk = l >> 4;
  int boff = (wmd & 1) * 64;

  char* ldsA = lds;
  char* ldsB = lds + 98304;

  floatx4 acc[8][4];
#pragma unroll
  for (int i = 0; i < 8; ++i)
#pragma unroll
    for (int jq = 0; jq < 4; ++jq) acc[i][jq] = (floatx4){0.f, 0.f, 0.f, 0.f};

  int kb0 = g * 1088;                          // NT = 17 tiles of 64

  // Prologue (FIFO order matters): A(0), B(0), A(1), B(1), A(2) = 20 loads
  stage_half(A,  s0,       kb0,       ldsA +     0, w, l);
  stage_half(A,  s0 + 128, kb0,       ldsA + 16384, w, l);
  stage_half(Bm, m0,       kb0,       ldsB +     0, w, l);
  stage_half(Bm, m0 + 128, kb0,       ldsB + 16384, w, l);
  stage_half(A,  s0,       kb0 + 64,  ldsA + 32768, w, l);
  stage_half(A,  s0 + 128, kb0 + 64,  ldsA + 49152, w, l);
  stage_half(Bm, m0,       kb0 + 64,  ldsB + 32768, w, l);
  stage_half(Bm, m0 + 128, kb0 + 64,  ldsB + 49152, w, l);
  stage_half(A,  s0,       kb0 + 128, ldsA + 65536, w, l);
  stage_half(A,  s0 + 128, kb0 + 128, ldsA + 81920, w, l);
  asm volatile("s_waitcnt vmcnt(12)" ::: "memory");   // A(0)+B(0) landed
  __builtin_amdgcn_s_barrier();

  int a3 = 0;                                  // t % 3, tracked incrementally
  for (int tt = 0; tt < 17; ++tt) {
    char* At = ldsA + a3 * 32768;
    char* Bt = ldsB + (tt & 1) * 32768;
    const char* Ar = At + wsd * 16384;
    const char* Br = Bt + (wmd >> 1) * 16384;
    bf16x8 aF[4][2], aG[4][2], bF[2][2], bG[2][2];
    // ph1: read aF + bF
    rda(aF, Ar, 0, lr16, lk); rdb(bF, Br, boff, lr16, lk);
    PH_PRE(); mfq<0, 0>(aF, bF, acc); PH_POST();
    // ph2: read aG
    rda(aG, Ar, 64, lr16, lk);
    PH_PRE(); mfq<4, 0>(aG, bF, acc); PH_POST();
    // ph3: read bG; stage A(tt+3) into its own (just-freed) A buffer
    rdb(bG, Br, boff + 32, lr16, lk);
    if (tt + 3 <= 16) {
      int kt3 = kb0 + (tt + 3) * 64;
      stage_half(A, s0,       kt3, At,         w, l);
      stage_half(A, s0 + 128, kt3, At + 16384, w, l);
    }
    PH_PRE(); mfq<0, 2>(aF, bG, acc); PH_POST();
    // ph4: stage B(tt+2) into its (just-freed) B buffer; counted wait
    if (tt + 2 <= 16) {
      int kt2 = kb0 + (tt + 2) * 64;
      stage_half(Bm, m0,       kt2, Bt,         w, l);
      stage_half(Bm, m0 + 128, kt2, Bt + 16384, w, l);
    }
    PH_PRE(); mfq<4, 2>(aG, bG, acc);
    if (tt <= 13)      asm volatile("s_waitcnt vmcnt(8)" ::: "memory");
    else if (tt == 14) asm volatile("s_waitcnt vmcnt(4)" ::: "memory");
    else if (tt == 15) asm volatile("s_waitcnt vmcnt(0)" ::: "memory");
    PH_POST();
    a3 = (a3 == 2) ? 0 : a3 + 1;
  }

  // C/D layout: col = lane&15, row = (lane>>4)*4 + q (verified r1-r9)
  u16* dst = (g < 2) ? zO : zW;
  int gg = g & 1;
#pragma unroll
  for (int ii = 0; ii < 8; ++ii)
#pragma unroll
    for (int jj = 0; jj < 4; ++jj) {
      int col  = m0 + wmd * 64 + jj * 16 + lr16;
      int rowb = s0 + wsd * 128 + ii * 16 + lk * 4;
#pragma unroll
      for (int q = 0; q < 4; ++q)
        dst[(size_t)(rowb + q) * 8192 + gg * 4096 + col] = f2bf_rne(acc[ii][jj][q]);
    }
}

// ---------------------------------------------------------------------------
// Kernel 5: out[s][i] = (Wscale/263.68)*SV[i]*H(sum of 4 partials)[i]
// Vectorized uint4 plane loads -> sum -> LDS bounce -> FWHT layout.
// zO aliases out rows: all reads precede the first barrier, writes after.
// ---------------------------------------------------------------------------
__global__ __launch_bounds__(256) void final_kernel(const float* __restrict__ SV,
                                                    const float* __restrict__ WscaleP,
                                                    const u16* __restrict__ zW,
                                                    float* __restrict__ out) {
  __shared__ float X[4096];
  int s = blockIdx.x, t = threadIdx.x, l = t & 63, w = t >> 6;
  const u16* zr = (const u16*)out + (size_t)s * 8192;
  const u16* zw = zW + (size_t)s * 8192;
#pragma unroll
  for (int c = 0; c < 2; ++c) {
    int j = (t + 256 * c) * 8;
    uint4 a0 = *(const uint4*)(zr + j);
    uint4 a1 = *(const uint4*)(zr + 4096 + j);
    uint4 b0 = *(const uint4*)(zw + j);
    uint4 b1 = *(const uint4*)(zw + 4096 + j);
    const unsigned* pa0 = (const unsigned*)&a0;
    const unsigned* pa1 = (const unsigned*)&a1;
    const unsigned* pb0 = (const unsigned*)&b0;
    const unsigned* pb1 = (const unsigned*)&b1;
#pragma unroll
    for (int q = 0; q < 4; ++q) {
      X[j + 2 * q] = (bf2f((u16)pa0[q]) + bf2f((u16)pa1[q])) +
                     (bf2f((u16)pb0[q]) + bf2f((u16)pb1[q]));
      X[j + 2 * q + 1] = (bf2f((u16)(pa0[q] >> 16)) + bf2f((u16)(pa1[q] >> 16))) +
                         (bf2f((u16)(pb0[q] >> 16)) + bf2f((u16)(pb1[q] >> 16)));
    }
  }
  __syncthreads();
  float v[16];
#pragma unroll
  for (int k = 0; k < 16; ++k) v[k] = X[(w * 16 + k) * 64 + l];
  __syncthreads();
  fwht4096_regs(v, X, w, l);
  float gscale = WscaleP[0] * (1.0f / 263.68f);
  float* orow = out + (size_t)s * 4096;
#pragma unroll
  for (int k = 0; k < 16; ++k) {
    int i = (w * 16 + k) * 64 + l;
    orow[i] = v[k] * gscale * SV[i];
  }
}

// ---------------------------------------------------------------------------
extern "C" void kernel_launch(void* const* d_in, const int* in_sizes, int n_in,
                              void* d_out, int out_size, void* d_ws, size_t ws_size,
                              hipStream_t stream) {
  const float* x      = (const float*)d_in[0];   // [1,1024,4096]
  const float* SU     = (const float*)d_in[1];   // [4096]
  const float* SV     = (const float*)d_in[2];   // [4096]
  const float* Wscale = (const float*)d_in[3];   // scalar
  const float* loraA  = (const float*)d_in[4];   // [4096,64]
  const float* loraB  = (const float*)d_in[5];   // [64,4096]
  const int*   Qidxs  = (const int*)d_in[6];     // [4096,512]
  const int*   grid   = (const int*)d_in[7];     // [256]
  float* out = (float*)d_out;

  char* ws = (char*)d_ws;
  u16* Wd = (u16*)ws;                                    // [4096][4352] = 35,651,584 B
  u16* u  = (u16*)(ws + 35651584);                       // [1024][4352] =  8,912,896 B
  u16* Bh = (u16*)(ws + 35651584 + 8912896);             // [64][4096]   =    524,288 B
  float* P = (float*)(ws + 35651584 + 8912896 + 524288); // [4][1024][64] = 1,048,576 B
  u16* zW = (u16*)(ws + 35651584 + 8912896 + 524288 + 1048576); // [1024][2][4096] bf16
  u16* zO = (u16*)out;                                   // [1024][2][4096] bf16, in-place

  prep_all_kernel<<<9280, 256, 0, stream>>>(x, SU, SV, Wscale, loraA, loraB,
                                            Qidxs, grid, Wd, u, Bh);
  dim3 lg(8, 4);
  lr_gemm_kernel<<<lg, 256, 0, stream>>>(u, Bh, P);
  lr_reduce_kernel<<<256, 256, 0, stream>>>(P, u);
  gemm_kernel<<<256, 512, 0, stream>>>(u, Wd, zO, zW);
  final_kernel<<<1024, 256, 0, stream>>>(SV, Wscale, zW, out);
}

// Round 11
// 80.651 us; speedup vs baseline: 1.0349x; 1.0349x over previous
//
#include <hip/hip_runtime.h>
#include <hip/hip_bf16.h>

typedef unsigned short u16;
typedef float  floatx4 __attribute__((ext_vector_type(4)));
typedef short  bf16x8  __attribute__((ext_vector_type(8)));

#define GK 4352   // 4096 + 64 lora cols + 192 zero pad (= 4 * 17 * 64)

__device__ __forceinline__ u16 f2bf_rne(float f) {
  union { float f; unsigned int u; } v; v.f = f;
  unsigned int r = v.u + 0x7FFFu + ((v.u >> 16) & 1u);
  return (u16)(r >> 16);
}
__device__ __forceinline__ float bf2f(u16 h) {
  union { unsigned int u; float f; } v; v.u = ((unsigned int)h) << 16;
  return v.f;
}

// ===========================================================================
// In-register FWHT-4096 per block (4 waves): H4096 = H64(rows) (x) H64(cols).
// ===========================================================================
__device__ __forceinline__ void fwht4096_regs(float v[16], float* X, int w, int l) {
#pragma unroll
  for (int h = 1; h < 64; h <<= 1) {
#pragma unroll
    for (int k = 0; k < 16; ++k) {
      float o = __shfl_xor(v[k], h, 64);
      v[k] = (l & h) ? (o - v[k]) : (v[k] + o);
    }
  }
#pragma unroll
  for (int k = 0; k < 16; ++k) X[(w * 16 + k) * 64 + l] = v[k];
  __syncthreads();
  float s4 = (w & 1) ? -1.f : 1.f;
  float s5 = (w & 2) ? -1.f : 1.f;
#pragma unroll
  for (int k = 0; k < 16; ++k) {
    float x00 = X[(k     ) * 64 + l];
    float x01 = X[(k + 16) * 64 + l];
    float x10 = X[(k + 32) * 64 + l];
    float x11 = X[(k + 48) * 64 + l];
    v[k] = (x00 + s4 * x01) + s5 * (x10 + s4 * x11);
  }
#pragma unroll
  for (int h = 1; h < 16; h <<= 1) {
#pragma unroll
    for (int k = 0; k < 16; ++k) {
      if (!(k & h)) { float a = v[k], b = v[k ^ h]; v[k] = a + b; v[k ^ h] = a - b; }
    }
  }
}

// ---------------------------------------------------------------------------
// Kernel 1 (fused): grid 9280 blocks, block-uniform branch:
//  bid 0..1023   : u[s] = bf16( H(x[s] o SU) / 64 )          (fwht_u)
//  bid 1024..1087: Wd tail col 4096+r, K-pad zero, Bh[r]      (prep_lora)
//  bid 1088..9279: decode E8P -> Wd integer weights (bf16)    (decode)
// ---------------------------------------------------------------------------
__global__ __launch_bounds__(256) void prep_all_kernel(
    const float* __restrict__ x, const float* __restrict__ SU,
    const float* __restrict__ SV, const float* __restrict__ WscaleP,
    const float* __restrict__ loraA, const float* __restrict__ loraB,
    const int* __restrict__ codes, const int* __restrict__ grid,
    u16* __restrict__ Wd, u16* __restrict__ u, u16* __restrict__ Bh) {
  __shared__ float X[4096];
  int bid = blockIdx.x, t = threadIdx.x, l = t & 63, w = t >> 6;

  if (bid < 1024) {
    int s = bid;
    const float* xr = x + (size_t)s * 4096;
    float v[16];
#pragma unroll
    for (int k = 0; k < 16; ++k) {
      int i = (w * 16 + k) * 64 + l;
      v[k] = xr[i] * SU[i];
    }
    fwht4096_regs(v, X, w, l);
    __syncthreads();
    u16* Xu = (u16*)X;
#pragma unroll
    for (int k = 0; k < 16; ++k)
      Xu[(w * 16 + k) * 64 + l] = f2bf_rne(v[k] * 0.015625f);
    __syncthreads();
    u16* ur = u + (size_t)s * GK;
#pragma unroll
    for (int c = 0; c < 2; ++c) {
      int j = (t + 256 * c) * 8;
      *(uint4*)(ur + j) = *(const uint4*)(Xu + j);
    }
  } else if (bid < 1088) {
    int r = bid - 1024;
    float v[16];
#pragma unroll
    for (int k = 0; k < 16; ++k) {
      int i = (w * 16 + k) * 64 + l;
      v[k] = loraA[(size_t)i * 64 + r] * SV[i];
    }
    fwht4096_regs(v, X, w, l);
    float factor = (0.8f * 263.68f / 4096.0f) / WscaleP[0];
#pragma unroll
    for (int k = 0; k < 16; ++k) {
      int i = (w * 16 + k) * 64 + l;
      Wd[(size_t)i * GK + 4096 + r] = f2bf_rne(v[k] * factor);
    }
    {
      uint4 zv = make_uint4(0, 0, 0, 0);
#pragma unroll
      for (int j = 0; j < 6; ++j) {
        int idx = t + 256 * j;
        int row = idx / 24, cs = idx % 24;
        uint4* p = (uint4*)(Wd + (size_t)(r * 64 + row) * GK + 4160) + cs;
        *p = zv;
      }
    }
    __syncthreads();
#pragma unroll
    for (int k = 0; k < 16; ++k) {
      int i = (w * 16 + k) * 64 + l;
      v[k] = loraB[(size_t)r * 4096 + i] * SU[i];
    }
    fwht4096_regs(v, X, w, l);
#pragma unroll
    for (int k = 0; k < 16; ++k) {
      int i = (w * 16 + k) * 64 + l;
      Bh[(size_t)r * 4096 + i] = f2bf_rne(v[k] * 0.015625f);
    }
  } else {
    int* sgrid = (int*)X;
    sgrid[t] = grid[t & 255];
    __syncthreads();
    int idx = (bid - 1088) * 256 + t;
    int c = codes[idx];
    int abs_idx   = c & 255;
    int sign_bits = (c >> 8) & 127;
    int dlt       = 2 * ((c >> 15) & 1) - 1;
    int packed    = sgrid[abs_idx];
    int par       = __popc(sign_bits) & 1;
    u16 wv[8];
#pragma unroll
    for (int j = 0; j < 8; ++j) {
      int nib = (packed >> (4 * j)) & 15;
      int neg = (j < 7) ? ((sign_bits >> j) & 1) : par;
      int val = (neg ? -2 * nib : 2 * nib) + dlt;
      wv[j] = f2bf_rne((float)val);
    }
    uint4 pk;
    pk.x = (unsigned)wv[0] | ((unsigned)wv[1] << 16);
    pk.y = (unsigned)wv[2] | ((unsigned)wv[3] << 16);
    pk.z = (unsigned)wv[4] | ((unsigned)wv[5] << 16);
    pk.w = (unsigned)wv[6] | ((unsigned)wv[7] << 16);
    int m = idx >> 9, g = idx & 511;
    ((uint4*)Wd)[(size_t)m * (GK / 8) + g] = pk;
  }
}

// ---------------------------------------------------------------------------
// Staging helpers (16B global_load_lds, XOR-swizzled source; verified r2-r10)
// ---------------------------------------------------------------------------
__device__ __forceinline__ void stage128(const u16* __restrict__ src, int rowBase,
                                         int kt, char* ldsBase, int wg, int l) {
#pragma unroll
  for (int it = 0; it < 4; ++it) {
    int ci  = it * 4 + wg;
    int row = ci * 8 + (l >> 3);
    int cg  = (l & 7) ^ ((l >> 3) & 7);
    const u16* gp = src + (size_t)(rowBase + row) * GK + kt + cg * 8;
    __builtin_amdgcn_global_load_lds(
        (const __attribute__((address_space(1))) void*)gp,
        (__attribute__((address_space(3))) void*)(ldsBase + ci * 1024), 16, 0, 0);
  }
}
__device__ __forceinline__ void stage64n(const u16* __restrict__ src,
                                         int kt, char* ldsBase, int wg, int l) {
#pragma unroll
  for (int it = 0; it < 2; ++it) {
    int ci  = it * 4 + wg;
    int row = ci * 8 + (l >> 3);
    int cg  = (l & 7) ^ ((l >> 3) & 7);
    const u16* gp = src + (size_t)row * 4096 + kt + cg * 8;
    __builtin_amdgcn_global_load_lds(
        (const __attribute__((address_space(1))) void*)gp,
        (__attribute__((address_space(3))) void*)(ldsBase + ci * 1024), 16, 0, 0);
  }
}
// 128-row x 64-col HALF-tile, 8-wave (512 thr) block: 2 loads/thread, 16 KB.
__device__ __forceinline__ void stage_half(const u16* src, int rowBase,
                                           int kt, char* slotBase, int w, int l) {
#pragma unroll
  for (int it = 0; it < 2; ++it) {
    int ci  = it * 8 + w;
    int row = ci * 8 + (l >> 3);
    int cg  = (l & 7) ^ ((l >> 3) & 7);
    const u16* gp = src + (size_t)(rowBase + row) * GK + kt + cg * 8;
    __builtin_amdgcn_global_load_lds(
        (const __attribute__((address_space(1))) void*)gp,
        (__attribute__((address_space(3))) void*)(slotBase + ci * 1024), 16, 0, 0);
  }
}

// ---------------------------------------------------------------------------
// Kernel 2: lr partials. P[by][s][r] = sum_{k in chunk by} u[s,k]*Bh[r,k]
// ---------------------------------------------------------------------------
__global__ __launch_bounds__(256) void lr_gemm_kernel(
    const u16* __restrict__ U,    // [1024][GK]
    const u16* __restrict__ Bh,   // [64][4096]
    float* __restrict__ P) {      // [4][1024][64]
  __shared__ char lds[49152];
  int t = threadIdx.x, w = t >> 6, l = t & 63;
  int s0 = blockIdx.x * 128, k0 = blockIdx.y * 1024;
  int lr16 = l & 15, lk = l >> 4;
  char* ldsA = lds;
  char* ldsB = lds + 32768;

  floatx4 acc[2][4];
#pragma unroll
  for (int i = 0; i < 2; ++i)
#pragma unroll
    for (int j = 0; j < 4; ++j) acc[i][j] = (floatx4){0.f, 0.f, 0.f, 0.f};

  const int NT = 16;
  stage128(U,  s0, k0,      ldsA,         w, l);
  stage64n(Bh,     k0,      ldsB,         w, l);
  stage128(U,  s0, k0 + 64, ldsA + 16384, w, l);
  stage64n(Bh,     k0 + 64, ldsB + 8192,  w, l);
  asm volatile("s_waitcnt vmcnt(6)" ::: "memory");
  __builtin_amdgcn_s_barrier();

  for (int i = 0; i < NT; ++i) {
    int buf = i & 1;
    const char* sAc = ldsA + buf * 16384;
    const char* sBc = ldsB + buf * 8192;
    bf16x8 a[2][2], b[4][2];
#pragma unroll
    for (int ii = 0; ii < 2; ++ii)
#pragma unroll
      for (int ks = 0; ks < 2; ++ks) {
        int row = w * 32 + ii * 16 + lr16;
        int kb  = ks * 64 + lk * 16;
        a[ii][ks] = *(const bf16x8*)(sAc + (row << 7) + (kb ^ ((row & 7) << 4)));
      }
#pragma unroll
    for (int jj = 0; jj < 4; ++jj)
#pragma unroll
      for (int ks = 0; ks < 2; ++ks) {
        int row = jj * 16 + lr16;
        int kb  = ks * 64 + lk * 16;
        b[jj][ks] = *(const bf16x8*)(sBc + (row << 7) + (kb ^ ((row & 7) << 4)));
      }
    asm volatile("s_waitcnt lgkmcnt(0)" ::: "memory");
    __builtin_amdgcn_sched_barrier(0);
    bool do_stage = (i + 2) < NT;
    if (do_stage) {
      __builtin_amdgcn_s_barrier();
      stage128(U,  s0, k0 + (i + 2) * 64, ldsA + buf * 16384, w, l);
      stage64n(Bh,     k0 + (i + 2) * 64, ldsB + buf * 8192,  w, l);
    }
#pragma unroll
    for (int ks = 0; ks < 2; ++ks)
#pragma unroll
      for (int ii = 0; ii < 2; ++ii)
#pragma unroll
        for (int jj = 0; jj < 4; ++jj)
          acc[ii][jj] = __builtin_amdgcn_mfma_f32_16x16x32_bf16(
              a[ii][ks], b[jj][ks], acc[ii][jj], 0, 0, 0);
    if (i + 1 < NT) {
      if (do_stage) asm volatile("s_waitcnt vmcnt(6)" ::: "memory");
      else          asm volatile("s_waitcnt vmcnt(0)" ::: "memory");
      __builtin_amdgcn_s_barrier();
    }
  }
  float* Pb = P + (size_t)blockIdx.y * 65536;
#pragma unroll
  for (int ii = 0; ii < 2; ++ii)
#pragma unroll
    for (int jj = 0; jj < 4; ++jj) {
      int col  = jj * 16 + lr16;
      int rowb = s0 + w * 32 + ii * 16 + lk * 4;
#pragma unroll
      for (int q = 0; q < 4; ++q)
        Pb[(size_t)(rowb + q) * 64 + col] = acc[ii][jj][q];
    }
}

// ---------------------------------------------------------------------------
// Kernel 3: GEMM partials, 256x256 tile, 8 waves, K-split 4, r8/r9-verified
// 8-phase schedule (39.4 us). NEW: g==3 blocks fold the lr tail reduction
// into their prologue (they alone stage u cols >= 4096, first at tile 13):
// sum 4 P planes -> bf16 u tail + pad zeros for their own 256 s-rows, then
// vmcnt(0) store-drain before any staging. Duplicate writes across the 16
// m-blocks are byte-identical (benign); same-XCD L2 makes them visible to
// this block's own global_load_lds.
// ---------------------------------------------------------------------------
__device__ __forceinline__ void rda(bf16x8 (&dst)[4][2], const char* base, int roff,
                                    int lr16, int lk) {
#pragma unroll
  for (int ii = 0; ii < 4; ++ii)
#pragma unroll
    for (int ks = 0; ks < 2; ++ks) {
      int r = roff + ii * 16 + lr16;
      dst[ii][ks] = *(const bf16x8*)(base + (r << 7) +
          ((ks * 64 + lk * 16) ^ ((r & 7) << 4)));
    }
}
__device__ __forceinline__ void rdb(bf16x8 (&dst)[2][2], const char* base, int roff,
                                    int lr16, int lk) {
#pragma unroll
  for (int jj = 0; jj < 2; ++jj)
#pragma unroll
    for (int ks = 0; ks < 2; ++ks) {
      int r = roff + jj * 16 + lr16;
      dst[jj][ks] = *(const bf16x8*)(base + (r << 7) +
          ((ks * 64 + lk * 16) ^ ((r & 7) << 4)));
    }
}
template<int IO, int JO>
__device__ __forceinline__ void mfq(const bf16x8 (&af)[4][2], const bf16x8 (&bf)[2][2],
                                    floatx4 (&acc)[8][4]) {
  __builtin_amdgcn_s_setprio(1);
#pragma unroll
  for (int ks = 0; ks < 2; ++ks)
#pragma unroll
    for (int ii = 0; ii < 4; ++ii)
#pragma unroll
      for (int jj = 0; jj < 2; ++jj)
        acc[IO + ii][JO + jj] = __builtin_amdgcn_mfma_f32_16x16x32_bf16(
            af[ii][ks], bf[jj][ks], acc[IO + ii][JO + jj], 0, 0, 0);
  __builtin_amdgcn_s_setprio(0);
}
#define PH_PRE()  do { __builtin_amdgcn_s_barrier(); \
                       asm volatile("s_waitcnt lgkmcnt(0)" ::: "memory"); } while (0)
#define PH_POST() __builtin_amdgcn_s_barrier()

__global__ __launch_bounds__(512, 2) void gemm_kernel(
    u16* U,                       // u [1024][GK] (reads; g==3 writes tail)
    const u16* __restrict__ Bm,   // Wd [4096][GK]
    const float* __restrict__ P,  // [4][1024][64] lr partials
    u16* __restrict__ zO,         // [1024][2][4096] bf16 (aliases d_out)
    u16* __restrict__ zW) {       // [1024][2][4096] bf16 (ws)
  __shared__ char lds[131072];    // buf0: A0 A1 B0 B1 | buf1: A0 A1 B0 B1 (16KB)
  int t = threadIdx.x, w = t >> 6, l = t & 63;
  int b = blockIdx.x;
  int xcd = b & 7, slot = b >> 3;
  int cell = slot >> 4, j4 = slot & 15;
  int x = (xcd & 3) * 4 + (j4 & 3);           // m-tile 0..15
  int g = (xcd >> 2) + 2 * cell;              // k-split 0..3
  int y = j4 >> 2;                            // s-tile 0..3
  int m0 = x * 256, s0 = y * 256;
  int wsd = w >> 2, wmd = w & 3;
  int lr16 = l & 15, lk = l >> 4;
  int boff = (wmd & 1) * 64;

  // ---- folded lr_reduce (g==3 only; tail cols staged first at tile 13) ----
  if (g == 3) {
#pragma unroll
    for (int e = 0; e < 32; ++e) {
      int idx = t + 512 * e;                  // 0..16383
      int ss = idx >> 6, rr = idx & 63;
      size_t pi = (size_t)(s0 + ss) * 64 + rr;
      float sum = P[pi] + P[65536 + pi] + P[131072 + pi] + P[196608 + pi];
      U[(size_t)(s0 + ss) * GK + 4096 + rr] = f2bf_rne(sum);
    }
    uint4 zv = make_uint4(0, 0, 0, 0);
#pragma unroll
    for (int e = 0; e < 12; ++e) {
      int idx = t + 512 * e;                  // 0..6143
      int row = idx / 24, cs = idx % 24;
      *((uint4*)(U + (size_t)(s0 + row) * GK + 4160) + cs) = zv;
    }
    asm volatile("s_waitcnt vmcnt(0)" ::: "memory");   // stores drained to L2
  }

  const char* A0b = lds + wsd * 16384;
  const char* B0b = lds + 32768 + (wmd >> 1) * 16384;
  const char* A1b = lds + 65536 + wsd * 16384;
  const char* B1b = lds + 98304 + (wmd >> 1) * 16384;

  floatx4 acc[8][4];
#pragma unroll
  for (int i = 0; i < 8; ++i)
#pragma unroll
    for (int jq = 0; jq < 4; ++jq) acc[i][jq] = (floatx4){0.f, 0.f, 0.f, 0.f};

  int kb0 = g * 1088;                          // 17 tiles * 64 per split

  stage_half(U,  s0,       kb0,      lds +      0, w, l);  // T0.A0
  stage_half(U,  s0 + 128, kb0,      lds +  16384, w, l);  // T0.A1
  stage_half(Bm, m0,       kb0,      lds +  32768, w, l);  // T0.B0
  stage_half(Bm, m0 + 128, kb0,      lds +  49152, w, l);  // T0.B1
  stage_half(Bm, m0,       kb0 + 64, lds +  98304, w, l);  // T1.B0
  stage_half(Bm, m0 + 128, kb0 + 64, lds + 114688, w, l);  // T1.B1
  asm volatile("s_waitcnt vmcnt(4)" ::: "memory");         // T0 landed
  __builtin_amdgcn_s_barrier();

  for (int j = 0; j < 8; ++j) {               // tiles 2j (buf0), 2j+1 (buf1)
    int kt1  = kb0 + (2 * j + 1) * 64;
    int ktn0 = kb0 + (2 * j + 2) * 64;
    int ktn1 = kb0 + (2 * j + 3) * 64;
    bf16x8 aF[4][2], aG[4][2], bF[2][2], bG[2][2];
    rda(aF, A0b, 0, lr16, lk); rdb(bF, B0b, boff, lr16, lk);
    stage_half(U, s0, kt1, lds + 65536, w, l);
    PH_PRE(); mfq<0, 0>(aF, bF, acc); PH_POST();
    rdb(bG, B0b, boff + 32, lr16, lk);
    stage_half(U, s0 + 128, kt1, lds + 81920, w, l);
    PH_PRE(); mfq<0, 2>(aF, bG, acc); PH_POST();
    rda(aG, A0b, 64, lr16, lk);
    stage_half(Bm, m0, ktn0, lds + 32768, w, l);
    PH_PRE(); mfq<4, 0>(aG, bF, acc); PH_POST();
    stage_half(Bm, m0 + 128, ktn0, lds + 49152, w, l);
    PH_PRE(); mfq<4, 2>(aG, bG, acc);
    asm volatile("s_waitcnt vmcnt(4)" ::: "memory");
    PH_POST();
    rda(aF, A1b, 0, lr16, lk); rdb(bF, B1b, boff, lr16, lk);
    stage_half(U, s0, ktn0, lds + 0, w, l);
    PH_PRE(); mfq<0, 0>(aF, bF, acc); PH_POST();
    rdb(bG, B1b, boff + 32, lr16, lk);
    stage_half(U, s0 + 128, ktn0, lds + 16384, w, l);
    PH_PRE(); mfq<0, 2>(aF, bG, acc); PH_POST();
    rda(aG, A1b, 64, lr16, lk);
    if (j < 7) stage_half(Bm, m0, ktn1, lds + 98304, w, l);
    PH_PRE(); mfq<4, 0>(aG, bF, acc); PH_POST();
    if (j < 7) stage_half(Bm, m0 + 128, ktn1, lds + 114688, w, l);
    PH_PRE(); mfq<4, 2>(aG, bG, acc);
    asm volatile("s_waitcnt vmcnt(4)" ::: "memory");
    PH_POST();
  }
  asm volatile("s_waitcnt vmcnt(0)" ::: "memory");
  __builtin_amdgcn_s_barrier();
  {
    bf16x8 aF[4][2], aG[4][2], bF[2][2], bG[2][2];
    rda(aF, A0b, 0, lr16, lk); rdb(bF, B0b, boff, lr16, lk);
    PH_PRE(); mfq<0, 0>(aF, bF, acc); PH_POST();
    rdb(bG, B0b, boff + 32, lr16, lk);
    PH_PRE(); mfq<0, 2>(aF, bG, acc); PH_POST();
    rda(aG, A0b, 64, lr16, lk);
    PH_PRE(); mfq<4, 0>(aG, bF, acc); PH_POST();
    PH_PRE(); mfq<4, 2>(aG, bG, acc);
  }
  // C/D layout: col = lane&15, row = (lane>>4)*4 + q (verified r1-r10)
  u16* dst = (g < 2) ? zO : zW;
  int gg = g & 1;
#pragma unroll
  for (int ii = 0; ii < 8; ++ii)
#pragma unroll
    for (int jj = 0; jj < 4; ++jj) {
      int col  = m0 + wmd * 64 + jj * 16 + lr16;
      int rowb = s0 + wsd * 128 + ii * 16 + lk * 4;
#pragma unroll
      for (int q = 0; q < 4; ++q)
        dst[(size_t)(rowb + q) * 8192 + gg * 4096 + col] = f2bf_rne(acc[ii][jj][q]);
    }
}

// ---------------------------------------------------------------------------
// Kernel 4: out[s][i] = (Wscale/263.68)*SV[i]*H(sum of 4 partials)[i]
// Vectorized uint4 plane loads -> sum -> LDS bounce -> FWHT layout.
// zO aliases out rows: all reads precede the first barrier, writes after.
// ---------------------------------------------------------------------------
__global__ __launch_bounds__(256) void final_kernel(const float* __restrict__ SV,
                                                    const float* __restrict__ WscaleP,
                                                    const u16* __restrict__ zW,
                                                    float* __restrict__ out) {
  __shared__ float X[4096];
  int s = blockIdx.x, t = threadIdx.x, l = t & 63, w = t >> 6;
  const u16* zr = (const u16*)out + (size_t)s * 8192;
  const u16* zw = zW + (size_t)s * 8192;
#pragma unroll
  for (int c = 0; c < 2; ++c) {
    int j = (t + 256 * c) * 8;
    uint4 a0 = *(const uint4*)(zr + j);
    uint4 a1 = *(const uint4*)(zr + 4096 + j);
    uint4 b0 = *(const uint4*)(zw + j);
    uint4 b1 = *(const uint4*)(zw + 4096 + j);
    const unsigned* pa0 = (const unsigned*)&a0;
    const unsigned* pa1 = (const unsigned*)&a1;
    const unsigned* pb0 = (const unsigned*)&b0;
    const unsigned* pb1 = (const unsigned*)&b1;
#pragma unroll
    for (int q = 0; q < 4; ++q) {
      X[j + 2 * q] = (bf2f((u16)pa0[q]) + bf2f((u16)pa1[q])) +
                     (bf2f((u16)pb0[q]) + bf2f((u16)pb1[q]));
      X[j + 2 * q + 1] = (bf2f((u16)(pa0[q] >> 16)) + bf2f((u16)(pa1[q] >> 16))) +
                         (bf2f((u16)(pb0[q] >> 16)) + bf2f((u16)(pb1[q] >> 16)));
    }
  }
  __syncthreads();
  float v[16];
#pragma unroll
  for (int k = 0; k < 16; ++k) v[k] = X[(w * 16 + k) * 64 + l];
  __syncthreads();
  fwht4096_regs(v, X, w, l);
  float gscale = WscaleP[0] * (1.0f / 263.68f);
  float* orow = out + (size_t)s * 4096;
#pragma unroll
  for (int k = 0; k < 16; ++k) {
    int i = (w * 16 + k) * 64 + l;
    orow[i] = v[k] * gscale * SV[i];
  }
}

// ---------------------------------------------------------------------------
extern "C" void kernel_launch(void* const* d_in, const int* in_sizes, int n_in,
                              void* d_out, int out_size, void* d_ws, size_t ws_size,
                              hipStream_t stream) {
  const float* x      = (const float*)d_in[0];   // [1,1024,4096]
  const float* SU     = (const float*)d_in[1];   // [4096]
  const float* SV     = (const float*)d_in[2];   // [4096]
  const float* Wscale = (const float*)d_in[3];   // scalar
  const float* loraA  = (const float*)d_in[4];   // [4096,64]
  const float* loraB  = (const float*)d_in[5];   // [64,4096]
  const int*   Qidxs  = (const int*)d_in[6];     // [4096,512]
  const int*   grid   = (const int*)d_in[7];     // [256]
  float* out = (float*)d_out;

  char* ws = (char*)d_ws;
  u16* Wd = (u16*)ws;                                    // [4096][4352] = 35,651,584 B
  u16* u  = (u16*)(ws + 35651584);                       // [1024][4352] =  8,912,896 B
  u16* Bh = (u16*)(ws + 35651584 + 8912896);             // [64][4096]   =    524,288 B
  float* P = (float*)(ws + 35651584 + 8912896 + 524288); // [4][1024][64] = 1,048,576 B
  u16* zW = (u16*)(ws + 35651584 + 8912896 + 524288 + 1048576); // [1024][2][4096] bf16
  u16* zO = (u16*)out;                                   // [1024][2][4096] bf16, in-place

  prep_all_kernel<<<9280, 256, 0, stream>>>(x, SU, SV, Wscale, loraA, loraB,
                                            Qidxs, grid, Wd, u, Bh);
  dim3 lg(8, 4);
  lr_gemm_kernel<<<lg, 256, 0, stream>>>(u, Bh, P);
  gemm_kernel<<<256, 512, 0, stream>>>(u, Wd, P, zO, zW);
  final_kernel<<<1024, 256, 0, stream>>>(SV, Wscale, zW, out);
}

// Round 12
// 78.027 us; speedup vs baseline: 1.0697x; 1.0336x over previous
//
#include <hip/hip_runtime.h>
#include <hip/hip_bf16.h>

typedef unsigned short u16;
typedef float  floatx4 __attribute__((ext_vector_type(4)));
typedef short  bf16x8  __attribute__((ext_vector_type(8)));

#define GK 4352   // 4096 + 64 lora cols + 192 zero pad (= 4 * 17 * 64)

__device__ __forceinline__ u16 f2bf_rne(float f) {
  union { float f; unsigned int u; } v; v.f = f;
  unsigned int r = v.u + 0x7FFFu + ((v.u >> 16) & 1u);
  return (u16)(r >> 16);
}
__device__ __forceinline__ float bf2f(u16 h) {
  union { unsigned int u; float f; } v; v.u = ((unsigned int)h) << 16;
  return v.f;
}

// ===========================================================================
// In-register FWHT-4096 per block (4 waves): H4096 = H64(rows) (x) H64(cols).
// ===========================================================================
__device__ __forceinline__ void fwht4096_regs(float v[16], float* X, int w, int l) {
#pragma unroll
  for (int h = 1; h < 64; h <<= 1) {
#pragma unroll
    for (int k = 0; k < 16; ++k) {
      float o = __shfl_xor(v[k], h, 64);
      v[k] = (l & h) ? (o - v[k]) : (v[k] + o);
    }
  }
#pragma unroll
  for (int k = 0; k < 16; ++k) X[(w * 16 + k) * 64 + l] = v[k];
  __syncthreads();
  float s4 = (w & 1) ? -1.f : 1.f;
  float s5 = (w & 2) ? -1.f : 1.f;
#pragma unroll
  for (int k = 0; k < 16; ++k) {
    float x00 = X[(k     ) * 64 + l];
    float x01 = X[(k + 16) * 64 + l];
    float x10 = X[(k + 32) * 64 + l];
    float x11 = X[(k + 48) * 64 + l];
    v[k] = (x00 + s4 * x01) + s5 * (x10 + s4 * x11);
  }
#pragma unroll
  for (int h = 1; h < 16; h <<= 1) {
#pragma unroll
    for (int k = 0; k < 16; ++k) {
      if (!(k & h)) { float a = v[k], b = v[k ^ h]; v[k] = a + b; v[k ^ h] = a - b; }
    }
  }
}

// ---------------------------------------------------------------------------
// Kernel 1 (fused): grid 9280 blocks, block-uniform branch:
//  bid 0..1023   : u[s] = bf16( H(x[s] o SU) / 64 )          (fwht_u)
//  bid 1024..1087: Wd tail col 4096+r, K-pad zero, Bh[r]      (prep_lora)
//  bid 1088..9279: decode E8P -> Wd integer weights (bf16)    (decode)
// ---------------------------------------------------------------------------
__global__ __launch_bounds__(256) void prep_all_kernel(
    const float* __restrict__ x, const float* __restrict__ SU,
    const float* __restrict__ SV, const float* __restrict__ WscaleP,
    const float* __restrict__ loraA, const float* __restrict__ loraB,
    const int* __restrict__ codes, const int* __restrict__ grid,
    u16* __restrict__ Wd, u16* __restrict__ u, u16* __restrict__ Bh) {
  __shared__ float X[4096];
  int bid = blockIdx.x, t = threadIdx.x, l = t & 63, w = t >> 6;

  if (bid < 1024) {
    int s = bid;
    const float* xr = x + (size_t)s * 4096;
    float v[16];
#pragma unroll
    for (int k = 0; k < 16; ++k) {
      int i = (w * 16 + k) * 64 + l;
      v[k] = xr[i] * SU[i];
    }
    fwht4096_regs(v, X, w, l);
    __syncthreads();
    u16* Xu = (u16*)X;
#pragma unroll
    for (int k = 0; k < 16; ++k)
      Xu[(w * 16 + k) * 64 + l] = f2bf_rne(v[k] * 0.015625f);
    __syncthreads();
    u16* ur = u + (size_t)s * GK;
#pragma unroll
    for (int c = 0; c < 2; ++c) {
      int j = (t + 256 * c) * 8;
      *(uint4*)(ur + j) = *(const uint4*)(Xu + j);
    }
  } else if (bid < 1088) {
    int r = bid - 1024;
    float v[16];
#pragma unroll
    for (int k = 0; k < 16; ++k) {
      int i = (w * 16 + k) * 64 + l;
      v[k] = loraA[(size_t)i * 64 + r] * SV[i];
    }
    fwht4096_regs(v, X, w, l);
    float factor = (0.8f * 263.68f / 4096.0f) / WscaleP[0];
#pragma unroll
    for (int k = 0; k < 16; ++k) {
      int i = (w * 16 + k) * 64 + l;
      Wd[(size_t)i * GK + 4096 + r] = f2bf_rne(v[k] * factor);
    }
    {
      uint4 zv = make_uint4(0, 0, 0, 0);
#pragma unroll
      for (int j = 0; j < 6; ++j) {
        int idx = t + 256 * j;
        int row = idx / 24, cs = idx % 24;
        uint4* p = (uint4*)(Wd + (size_t)(r * 64 + row) * GK + 4160) + cs;
        *p = zv;
      }
    }
    __syncthreads();
#pragma unroll
    for (int k = 0; k < 16; ++k) {
      int i = (w * 16 + k) * 64 + l;
      v[k] = loraB[(size_t)r * 4096 + i] * SU[i];
    }
    fwht4096_regs(v, X, w, l);
#pragma unroll
    for (int k = 0; k < 16; ++k) {
      int i = (w * 16 + k) * 64 + l;
      Bh[(size_t)r * 4096 + i] = f2bf_rne(v[k] * 0.015625f);
    }
  } else {
    int* sgrid = (int*)X;
    sgrid[t] = grid[t & 255];
    __syncthreads();
    int idx = (bid - 1088) * 256 + t;
    int c = codes[idx];
    int abs_idx   = c & 255;
    int sign_bits = (c >> 8) & 127;
    int dlt       = 2 * ((c >> 15) & 1) - 1;
    int packed    = sgrid[abs_idx];
    int par       = __popc(sign_bits) & 1;
    u16 wv[8];
#pragma unroll
    for (int j = 0; j < 8; ++j) {
      int nib = (packed >> (4 * j)) & 15;
      int neg = (j < 7) ? ((sign_bits >> j) & 1) : par;
      int val = (neg ? -2 * nib : 2 * nib) + dlt;
      wv[j] = f2bf_rne((float)val);
    }
    uint4 pk;
    pk.x = (unsigned)wv[0] | ((unsigned)wv[1] << 16);
    pk.y = (unsigned)wv[2] | ((unsigned)wv[3] << 16);
    pk.z = (unsigned)wv[4] | ((unsigned)wv[5] << 16);
    pk.w = (unsigned)wv[6] | ((unsigned)wv[7] << 16);
    int m = idx >> 9, g = idx & 511;
    ((uint4*)Wd)[(size_t)m * (GK / 8) + g] = pk;
  }
}

// ---------------------------------------------------------------------------
// Staging helpers (16B global_load_lds, XOR-swizzled source; verified r2-r11)
// ---------------------------------------------------------------------------
__device__ __forceinline__ void stage128(const u16* __restrict__ src, int rowBase,
                                         int kt, char* ldsBase, int wg, int l) {
#pragma unroll
  for (int it = 0; it < 4; ++it) {
    int ci  = it * 4 + wg;
    int row = ci * 8 + (l >> 3);
    int cg  = (l & 7) ^ ((l >> 3) & 7);
    const u16* gp = src + (size_t)(rowBase + row) * GK + kt + cg * 8;
    __builtin_amdgcn_global_load_lds(
        (const __attribute__((address_space(1))) void*)gp,
        (__attribute__((address_space(3))) void*)(ldsBase + ci * 1024), 16, 0, 0);
  }
}
__device__ __forceinline__ void stage64n(const u16* __restrict__ src,
                                         int kt, char* ldsBase, int wg, int l) {
#pragma unroll
  for (int it = 0; it < 2; ++it) {
    int ci  = it * 4 + wg;
    int row = ci * 8 + (l >> 3);
    int cg  = (l & 7) ^ ((l >> 3) & 7);
    const u16* gp = src + (size_t)row * 4096 + kt + cg * 8;
    __builtin_amdgcn_global_load_lds(
        (const __attribute__((address_space(1))) void*)gp,
        (__attribute__((address_space(3))) void*)(ldsBase + ci * 1024), 16, 0, 0);
  }
}
// 128-row x 64-col HALF-tile, 8-wave (512 thr) block: 2 loads/thread, 16 KB.
__device__ __forceinline__ void stage_half(const u16* __restrict__ src, int rowBase,
                                           int kt, char* slotBase, int w, int l) {
#pragma unroll
  for (int it = 0; it < 2; ++it) {
    int ci  = it * 8 + w;
    int row = ci * 8 + (l >> 3);
    int cg  = (l & 7) ^ ((l >> 3) & 7);
    const u16* gp = src + (size_t)(rowBase + row) * GK + kt + cg * 8;
    __builtin_amdgcn_global_load_lds(
        (const __attribute__((address_space(1))) void*)gp,
        (__attribute__((address_space(3))) void*)(slotBase + ci * 1024), 16, 0, 0);
  }
}

// ---------------------------------------------------------------------------
// Kernel 2: lr partials. P[by][s][r] = sum_{k in 512-chunk by} u[s,k]*Bh[r,k]
// Grid (8 s-tiles, 8 k-chunks) = 64 blocks (2x the r9 parallelism).
// ---------------------------------------------------------------------------
__global__ __launch_bounds__(256) void lr_gemm_kernel(
    const u16* __restrict__ U,    // [1024][GK]
    const u16* __restrict__ Bh,   // [64][4096]
    float* __restrict__ P) {      // [8][1024][64]
  __shared__ char lds[49152];
  int t = threadIdx.x, w = t >> 6, l = t & 63;
  int s0 = blockIdx.x * 128, k0 = blockIdx.y * 512;
  int lr16 = l & 15, lk = l >> 4;
  char* ldsA = lds;
  char* ldsB = lds + 32768;

  floatx4 acc[2][4];
#pragma unroll
  for (int i = 0; i < 2; ++i)
#pragma unroll
    for (int j = 0; j < 4; ++j) acc[i][j] = (floatx4){0.f, 0.f, 0.f, 0.f};

  const int NT = 8;    // 8 * 64 = 512
  stage128(U,  s0, k0,      ldsA,         w, l);
  stage64n(Bh,     k0,      ldsB,         w, l);
  stage128(U,  s0, k0 + 64, ldsA + 16384, w, l);
  stage64n(Bh,     k0 + 64, ldsB + 8192,  w, l);
  asm volatile("s_waitcnt vmcnt(6)" ::: "memory");
  __builtin_amdgcn_s_barrier();

  for (int i = 0; i < NT; ++i) {
    int buf = i & 1;
    const char* sAc = ldsA + buf * 16384;
    const char* sBc = ldsB + buf * 8192;
    bf16x8 a[2][2], b[4][2];
#pragma unroll
    for (int ii = 0; ii < 2; ++ii)
#pragma unroll
      for (int ks = 0; ks < 2; ++ks) {
        int row = w * 32 + ii * 16 + lr16;
        int kb  = ks * 64 + lk * 16;
        a[ii][ks] = *(const bf16x8*)(sAc + (row << 7) + (kb ^ ((row & 7) << 4)));
      }
#pragma unroll
    for (int jj = 0; jj < 4; ++jj)
#pragma unroll
      for (int ks = 0; ks < 2; ++ks) {
        int row = jj * 16 + lr16;
        int kb  = ks * 64 + lk * 16;
        b[jj][ks] = *(const bf16x8*)(sBc + (row << 7) + (kb ^ ((row & 7) << 4)));
      }
    asm volatile("s_waitcnt lgkmcnt(0)" ::: "memory");
    __builtin_amdgcn_sched_barrier(0);
    bool do_stage = (i + 2) < NT;
    if (do_stage) {
      __builtin_amdgcn_s_barrier();
      stage128(U,  s0, k0 + (i + 2) * 64, ldsA + buf * 16384, w, l);
      stage64n(Bh,     k0 + (i + 2) * 64, ldsB + buf * 8192,  w, l);
    }
#pragma unroll
    for (int ks = 0; ks < 2; ++ks)
#pragma unroll
      for (int ii = 0; ii < 2; ++ii)
#pragma unroll
        for (int jj = 0; jj < 4; ++jj)
          acc[ii][jj] = __builtin_amdgcn_mfma_f32_16x16x32_bf16(
              a[ii][ks], b[jj][ks], acc[ii][jj], 0, 0, 0);
    if (i + 1 < NT) {
      if (do_stage) asm volatile("s_waitcnt vmcnt(6)" ::: "memory");
      else          asm volatile("s_waitcnt vmcnt(0)" ::: "memory");
      __builtin_amdgcn_s_barrier();
    }
  }
  float* Pb = P + (size_t)blockIdx.y * 65536;
#pragma unroll
  for (int ii = 0; ii < 2; ++ii)
#pragma unroll
    for (int jj = 0; jj < 4; ++jj) {
      int col  = jj * 16 + lr16;
      int rowb = s0 + w * 32 + ii * 16 + lk * 4;
#pragma unroll
      for (int q = 0; q < 4; ++q)
        Pb[(size_t)(rowb + q) * 64 + col] = acc[ii][jj][q];
    }
}

// ---------------------------------------------------------------------------
// Kernel 3: lr tail: u[s][4096+r] = bf16( sum_{c<8} P[c][s][r] ); zero K pad.
// ---------------------------------------------------------------------------
__global__ void lr_reduce_kernel(const float* __restrict__ P, u16* __restrict__ u) {
  int idx = blockIdx.x * 256 + threadIdx.x;   // 0..65535
  float s = 0.f;
#pragma unroll
  for (int c = 0; c < 8; ++c) s += P[(size_t)c * 65536 + idx];
  int ss = idx >> 6, rr = idx & 63;
  u16* row = u + (size_t)ss * GK;
  row[4096 + rr] = f2bf_rne(s);
  row[4160 + rr] = 0;                         // K pad
  row[4224 + rr] = 0;
  row[4288 + rr] = 0;
}

// ---------------------------------------------------------------------------
// Kernel 4: GEMM partials, 256x256 tile, 8 waves, K-split 4, r9-verified
// 8-phase schedule (39.4 us measured) + m201 lgkmcnt(8) hint in 12-read
// phases (ph1/ph5/tail-ph1).
// ---------------------------------------------------------------------------
__device__ __forceinline__ void rda(bf16x8 (&dst)[4][2], const char* base, int roff,
                                    int lr16, int lk) {
#pragma unroll
  for (int ii = 0; ii < 4; ++ii)
#pragma unroll
    for (int ks = 0; ks < 2; ++ks) {
      int r = roff + ii * 16 + lr16;
      dst[ii][ks] = *(const bf16x8*)(base + (r << 7) +
          ((ks * 64 + lk * 16) ^ ((r & 7) << 4)));
    }
}
__device__ __forceinline__ void rdb(bf16x8 (&dst)[2][2], const char* base, int roff,
                                    int lr16, int lk) {
#pragma unroll
  for (int jj = 0; jj < 2; ++jj)
#pragma unroll
    for (int ks = 0; ks < 2; ++ks) {
      int r = roff + jj * 16 + lr16;
      dst[jj][ks] = *(const bf16x8*)(base + (r << 7) +
          ((ks * 64 + lk * 16) ^ ((r & 7) << 4)));
    }
}
template<int IO, int JO>
__device__ __forceinline__ void mfq(const bf16x8 (&af)[4][2], const bf16x8 (&bf)[2][2],
                                    floatx4 (&acc)[8][4]) {
  __builtin_amdgcn_s_setprio(1);
#pragma unroll
  for (int ks = 0; ks < 2; ++ks)
#pragma unroll
    for (int ii = 0; ii < 4; ++ii)
#pragma unroll
      for (int jj = 0; jj < 2; ++jj)
        acc[IO + ii][JO + jj] = __builtin_amdgcn_mfma_f32_16x16x32_bf16(
            af[ii][ks], bf[jj][ks], acc[IO + ii][JO + jj], 0, 0, 0);
  __builtin_amdgcn_s_setprio(0);
}
#define PH_PRE()  do { __builtin_amdgcn_s_barrier(); \
                       asm volatile("s_waitcnt lgkmcnt(0)" ::: "memory"); } while (0)
#define PH_POST() __builtin_amdgcn_s_barrier()
#define LGKM_HINT() asm volatile("s_waitcnt lgkmcnt(8)" ::: "memory")

__global__ __launch_bounds__(512, 2) void gemm_kernel(
    const u16* __restrict__ A,    // u  [1024][GK]
    const u16* __restrict__ Bm,   // Wd [4096][GK]
    u16* __restrict__ zO,         // [1024][2][4096] bf16 (aliases d_out)
    u16* __restrict__ zW) {       // [1024][2][4096] bf16 (ws)
  __shared__ char lds[131072];    // buf0: A0 A1 B0 B1 | buf1: A0 A1 B0 B1 (16KB)
  int t = threadIdx.x, w = t >> 6, l = t & 63;
  int b = blockIdx.x;
  int xcd = b & 7, slot = b >> 3;
  int cell = slot >> 4, j4 = slot & 15;
  int x = (xcd & 3) * 4 + (j4 & 3);           // m-tile 0..15
  int g = (xcd >> 2) + 2 * cell;              // k-split 0..3
  int y = j4 >> 2;                            // s-tile 0..3
  int m0 = x * 256, s0 = y * 256;
  int wsd = w >> 2, wmd = w & 3;
  int lr16 = l & 15, lk = l >> 4;
  int boff = (wmd & 1) * 64;

  const char* A0b = lds + wsd * 16384;
  const char* B0b = lds + 32768 + (wmd >> 1) * 16384;
  const char* A1b = lds + 65536 + wsd * 16384;
  const char* B1b = lds + 98304 + (wmd >> 1) * 16384;

  floatx4 acc[8][4];
#pragma unroll
  for (int i = 0; i < 8; ++i)
#pragma unroll
    for (int jq = 0; jq < 4; ++jq) acc[i][jq] = (floatx4){0.f, 0.f, 0.f, 0.f};

  int kb0 = g * 1088;                          // 17 tiles * 64 per split

  stage_half(A,  s0,       kb0,      lds +      0, w, l);  // T0.A0
  stage_half(A,  s0 + 128, kb0,      lds +  16384, w, l);  // T0.A1
  stage_half(Bm, m0,       kb0,      lds +  32768, w, l);  // T0.B0
  stage_half(Bm, m0 + 128, kb0,      lds +  49152, w, l);  // T0.B1
  stage_half(Bm, m0,       kb0 + 64, lds +  98304, w, l);  // T1.B0
  stage_half(Bm, m0 + 128, kb0 + 64, lds + 114688, w, l);  // T1.B1
  asm volatile("s_waitcnt vmcnt(4)" ::: "memory");         // T0 landed
  __builtin_amdgcn_s_barrier();

  for (int j = 0; j < 8; ++j) {               // tiles 2j (buf0), 2j+1 (buf1)
    int kt1  = kb0 + (2 * j + 1) * 64;
    int ktn0 = kb0 + (2 * j + 2) * 64;
    int ktn1 = kb0 + (2 * j + 3) * 64;
    bf16x8 aF[4][2], aG[4][2], bF[2][2], bG[2][2];
    // ph1 (12 ds_reads -> lgkm hint)
    rda(aF, A0b, 0, lr16, lk); rdb(bF, B0b, boff, lr16, lk);
    stage_half(A, s0, kt1, lds + 65536, w, l);
    LGKM_HINT();
    PH_PRE(); mfq<0, 0>(aF, bF, acc); PH_POST();
    rdb(bG, B0b, boff + 32, lr16, lk);
    stage_half(A, s0 + 128, kt1, lds + 81920, w, l);
    PH_PRE(); mfq<0, 2>(aF, bG, acc); PH_POST();
    rda(aG, A0b, 64, lr16, lk);
    stage_half(Bm, m0, ktn0, lds + 32768, w, l);
    PH_PRE(); mfq<4, 0>(aG, bF, acc); PH_POST();
    stage_half(Bm, m0 + 128, ktn0, lds + 49152, w, l);
    PH_PRE(); mfq<4, 2>(aG, bG, acc);
    asm volatile("s_waitcnt vmcnt(4)" ::: "memory");
    PH_POST();
    // ph5 (12 ds_reads -> lgkm hint)
    rda(aF, A1b, 0, lr16, lk); rdb(bF, B1b, boff, lr16, lk);
    stage_half(A, s0, ktn0, lds + 0, w, l);
    LGKM_HINT();
    PH_PRE(); mfq<0, 0>(aF, bF, acc); PH_POST();
    rdb(bG, B1b, boff + 32, lr16, lk);
    stage_half(A, s0 + 128, ktn0, lds + 16384, w, l);
    PH_PRE(); mfq<0, 2>(aF, bG, acc); PH_POST();
    rda(aG, A1b, 64, lr16, lk);
    if (j < 7) stage_half(Bm, m0, ktn1, lds + 98304, w, l);
    PH_PRE(); mfq<4, 0>(aG, bF, acc); PH_POST();
    if (j < 7) stage_half(Bm, m0 + 128, ktn1, lds + 114688, w, l);
    PH_PRE(); mfq<4, 2>(aG, bG, acc);
    asm volatile("s_waitcnt vmcnt(4)" ::: "memory");
    PH_POST();
  }
  asm volatile("s_waitcnt vmcnt(0)" ::: "memory");
  __builtin_amdgcn_s_barrier();
  {
    bf16x8 aF[4][2], aG[4][2], bF[2][2], bG[2][2];
    rda(aF, A0b, 0, lr16, lk); rdb(bF, B0b, boff, lr16, lk);
    LGKM_HINT();
    PH_PRE(); mfq<0, 0>(aF, bF, acc); PH_POST();
    rdb(bG, B0b, boff + 32, lr16, lk);
    PH_PRE(); mfq<0, 2>(aF, bG, acc); PH_POST();
    rda(aG, A0b, 64, lr16, lk);
    PH_PRE(); mfq<4, 0>(aG, bF, acc); PH_POST();
    PH_PRE(); mfq<4, 2>(aG, bG, acc);
  }
  // C/D layout: col = lane&15, row = (lane>>4)*4 + q (verified r1-r11)
  u16* dst = (g < 2) ? zO : zW;
  int gg = g & 1;
#pragma unroll
  for (int ii = 0; ii < 8; ++ii)
#pragma unroll
    for (int jj = 0; jj < 4; ++jj) {
      int col  = m0 + wmd * 64 + jj * 16 + lr16;
      int rowb = s0 + wsd * 128 + ii * 16 + lk * 4;
#pragma unroll
      for (int q = 0; q < 4; ++q)
        dst[(size_t)(rowb + q) * 8192 + gg * 4096 + col] = f2bf_rne(acc[ii][jj][q]);
    }
}

// ---------------------------------------------------------------------------
// Kernel 5: out[s][i] = (Wscale/263.68)*SV[i]*H(sum of 4 partials)[i]
// Vectorized uint4 plane loads -> sum -> LDS bounce -> FWHT layout.
// zO aliases out rows: all reads precede the first barrier, writes after.
// ---------------------------------------------------------------------------
__global__ __launch_bounds__(256) void final_kernel(const float* __restrict__ SV,
                                                    const float* __restrict__ WscaleP,
                                                    const u16* __restrict__ zW,
                                                    float* __restrict__ out) {
  __shared__ float X[4096];
  int s = blockIdx.x, t = threadIdx.x, l = t & 63, w = t >> 6;
  const u16* zr = (const u16*)out + (size_t)s * 8192;
  const u16* zw = zW + (size_t)s * 8192;
#pragma unroll
  for (int c = 0; c < 2; ++c) {
    int j = (t + 256 * c) * 8;
    uint4 a0 = *(const uint4*)(zr + j);
    uint4 a1 = *(const uint4*)(zr + 4096 + j);
    uint4 b0 = *(const uint4*)(zw + j);
    uint4 b1 = *(const uint4*)(zw + 4096 + j);
    const unsigned* pa0 = (const unsigned*)&a0;
    const unsigned* pa1 = (const unsigned*)&a1;
    const unsigned* pb0 = (const unsigned*)&b0;
    const unsigned* pb1 = (const unsigned*)&b1;
#pragma unroll
    for (int q = 0; q < 4; ++q) {
      X[j + 2 * q] = (bf2f((u16)pa0[q]) + bf2f((u16)pa1[q])) +
                     (bf2f((u16)pb0[q]) + bf2f((u16)pb1[q]));
      X[j + 2 * q + 1] = (bf2f((u16)(pa0[q] >> 16)) + bf2f((u16)(pa1[q] >> 16))) +
                         (bf2f((u16)(pb0[q] >> 16)) + bf2f((u16)(pb1[q] >> 16)));
    }
  }
  __syncthreads();
  float v[16];
#pragma unroll
  for (int k = 0; k < 16; ++k) v[k] = X[(w * 16 + k) * 64 + l];
  __syncthreads();
  fwht4096_regs(v, X, w, l);
  float gscale = WscaleP[0] * (1.0f / 263.68f);
  float* orow = out + (size_t)s * 4096;
#pragma unroll
  for (int k = 0; k < 16; ++k) {
    int i = (w * 16 + k) * 64 + l;
    orow[i] = v[k] * gscale * SV[i];
  }
}

// ---------------------------------------------------------------------------
extern "C" void kernel_launch(void* const* d_in, const int* in_sizes, int n_in,
                              void* d_out, int out_size, void* d_ws, size_t ws_size,
                              hipStream_t stream) {
  const float* x      = (const float*)d_in[0];   // [1,1024,4096]
  const float* SU     = (const float*)d_in[1];   // [4096]
  const float* SV     = (const float*)d_in[2];   // [4096]
  const float* Wscale = (const float*)d_in[3];   // scalar
  const float* loraA  = (const float*)d_in[4];   // [4096,64]
  const float* loraB  = (const float*)d_in[5];   // [64,4096]
  const int*   Qidxs  = (const int*)d_in[6];     // [4096,512]
  const int*   grid   = (const int*)d_in[7];     // [256]
  float* out = (float*)d_out;

  char* ws = (char*)d_ws;
  u16* Wd = (u16*)ws;                                    // [4096][4352] = 35,651,584 B
  u16* u  = (u16*)(ws + 35651584);                       // [1024][4352] =  8,912,896 B
  u16* Bh = (u16*)(ws + 35651584 + 8912896);             // [64][4096]   =    524,288 B
  float* P = (float*)(ws + 35651584 + 8912896 + 524288); // [8][1024][64] = 2,097,152 B
  u16* zW = (u16*)(ws + 35651584 + 8912896 + 524288 + 2097152); // [1024][2][4096] bf16
  u16* zO = (u16*)out;                                   // [1024][2][4096] bf16, in-place

  prep_all_kernel<<<9280, 256, 0, stream>>>(x, SU, SV, Wscale, loraA, loraB,
                                            Qidxs, grid, Wd, u, Bh);
  dim3 lg(8, 8);
  lr_gemm_kernel<<<lg, 256, 0, stream>>>(u, Bh, P);
  lr_reduce_kernel<<<256, 256, 0, stream>>>(P, u);
  gemm_kernel<<<256, 512, 0, stream>>>(u, Wd, zO, zW);
  final_kernel<<<1024, 256, 0, stream>>>(SV, Wscale, zW, out);
}